// Round 1
// baseline (333.649 us; speedup 1.0000x reference)
//
#include <hip/hip_runtime.h>
#include <hip/hip_bf16.h>

#define N_NODES_C 100000
#define N_RELS_C  237
#define N_EDGES_C 500000
#define D 128

// ============ K0: fuse weights =============
// Wf[k][j]      (j<128)  = sum_i W_ent[k][i] * W_ent2[i][j]        (-> A path)
// Wf[k][128+j]           = sum_i W_ent[k][i] * W_ent2[128+i][j]    (-> B path)
// WR[k][j]               = sum_i W_rel[k][i] * W_ent2[256+i][j]    (-> R path)
// biasC[j] = b_ent@(W1+W2) + b_rel@W3 + b_ent2
__global__ void k_fuse_w(const float* __restrict__ W_ent, const float* __restrict__ W_rel,
                         const float* __restrict__ W_ent2,
                         const float* __restrict__ b_ent, const float* __restrict__ b_rel,
                         const float* __restrict__ b_ent2,
                         float* __restrict__ Wf, float* __restrict__ WR,
                         float* __restrict__ biasC) {
    int j = threadIdx.x;       // 0..127 output col
    int k = blockIdx.x;        // 0..127 row
    int which = blockIdx.y;    // 0..3
    if (which == 0) {
        float acc = 0.f;
        for (int i = 0; i < D; ++i) acc += W_ent[k*D+i] * W_ent2[i*D+j];
        Wf[k*256 + j] = acc;
    } else if (which == 1) {
        float acc = 0.f;
        for (int i = 0; i < D; ++i) acc += W_ent[k*D+i] * W_ent2[(D+i)*D+j];
        Wf[k*256 + D + j] = acc;
    } else if (which == 2) {
        float acc = 0.f;
        for (int i = 0; i < D; ++i) acc += W_rel[k*D+i] * W_ent2[(2*D+i)*D+j];
        WR[k*D + j] = acc;
    } else if (k == 0) {
        float acc = b_ent2[j];
        for (int i = 0; i < D; ++i) {
            acc += b_ent[i] * (W_ent2[i*D+j] + W_ent2[(D+i)*D+j]);
            acc += b_rel[i] * W_ent2[(2*D+i)*D+j];
        }
        biasC[j] = acc;
    }
}

// ============ K0b: relation table + attention scalars =============
// Rm[r][j] = rel_embed[r] @ WR ; sR[r] = Rm[r] @ a_w
// av1[k] = Wf[k][0:128] @ a_w ; av2[k] = Wf[k][128:256] @ a_w
// sConst = biasC @ a_w + a_b
__global__ void k_rel_scalars(const float* __restrict__ rel_embed,
                              const float* __restrict__ a_w, const float* __restrict__ a_b,
                              const float* __restrict__ Wf, const float* __restrict__ WR,
                              const float* __restrict__ biasC,
                              float* __restrict__ Rm, float* __restrict__ av1,
                              float* __restrict__ av2, float* __restrict__ sR,
                              float* __restrict__ sConst) {
    int j = threadIdx.x;   // 128 threads
    int b = blockIdx.x;    // 0..239
    __shared__ float red[128];
    if (b < N_RELS_C) {
        float acc = 0.f;
        for (int k = 0; k < D; ++k) acc += rel_embed[b*D+k] * WR[k*D+j];
        Rm[b*D+j] = acc;
        red[j] = acc * a_w[j];
        __syncthreads();
        for (int s = 64; s > 0; s >>= 1) { if (j < s) red[j] += red[j+s]; __syncthreads(); }
        if (j == 0) sR[b] = red[0];
    } else if (b == N_RELS_C) {
        float acc = 0.f;
        for (int t = 0; t < D; ++t) acc += Wf[j*256 + t] * a_w[t];
        av1[j] = acc;
    } else if (b == N_RELS_C + 1) {
        float acc = 0.f;
        for (int t = 0; t < D; ++t) acc += Wf[j*256 + D + t] * a_w[t];
        av2[j] = acc;
    } else {
        red[j] = biasC[j] * a_w[j];
        __syncthreads();
        for (int s = 64; s > 0; s >>= 1) { if (j < s) red[j] += red[j+s]; __syncthreads(); }
        if (j == 0) sConst[0] = red[0] + a_b[0];
    }
}

// ============ K1: node GEMM: [An|Bn] = ent_embed(100000x128) @ Wf(128x256) =============
// block: 256 thr, 64 nodes x 256 cols; thread tile 8 nodes x (4 A-cols + 4 B-cols)
__global__ __launch_bounds__(256) void k1_gemm(const float* __restrict__ ent,
                                               const float* __restrict__ Wf,
                                               float* __restrict__ An, float* __restrict__ Bn,
                                               int n_nodes) {
    __shared__ float Wl[32*256];   // [kc][256]
    __shared__ float El[32*68];    // [kc][node], stride 68 (16B-aligned rows, bank-skewed)
    int tid = threadIdx.x;
    int tx = tid & 31;             // col group: cols tx*4 (A) and 128+tx*4 (B)
    int ty = tid >> 5;             // node group: nodes ty*8..ty*8+7
    int n0 = blockIdx.x * 64;

    float acc[8][8];
#pragma unroll
    for (int m = 0; m < 8; ++m)
#pragma unroll
        for (int c = 0; c < 8; ++c) acc[m][c] = 0.f;

    for (int kc = 0; kc < D; kc += 32) {
        // stage W chunk 32x256
#pragma unroll
        for (int u = 0; u < 8; ++u) {
            int idx = tid + u*256;        // float4 index 0..2047
            int r = idx >> 6;             // row 0..31
            int cq = idx & 63;            // float4 col 0..63
            *(float4*)&Wl[r*256 + cq*4] = *(const float4*)&Wf[(kc+r)*256 + cq*4];
        }
        // stage ent chunk transposed: El[k][m]
#pragma unroll
        for (int u = 0; u < 2; ++u) {
            int idx = tid + u*256;        // 0..511
            int m  = idx >> 3;            // node 0..63
            int kq = idx & 7;             // float4 group 0..7
            int n = n0 + m;
            float4 e = make_float4(0.f,0.f,0.f,0.f);
            if (n < n_nodes) e = *(const float4*)&ent[n*D + kc + kq*4];
            El[(kq*4+0)*68 + m] = e.x;
            El[(kq*4+1)*68 + m] = e.y;
            El[(kq*4+2)*68 + m] = e.z;
            El[(kq*4+3)*68 + m] = e.w;
        }
        __syncthreads();
#pragma unroll 4
        for (int k = 0; k < 32; ++k) {
            float4 wA = *(float4*)&Wl[k*256 + tx*4];
            float4 wB = *(float4*)&Wl[k*256 + 128 + tx*4];
            float4 eA = *(float4*)&El[k*68 + ty*8];
            float4 eB = *(float4*)&El[k*68 + ty*8 + 4];
            float ev[8] = {eA.x,eA.y,eA.z,eA.w,eB.x,eB.y,eB.z,eB.w};
            float wv[8] = {wA.x,wA.y,wA.z,wA.w,wB.x,wB.y,wB.z,wB.w};
#pragma unroll
            for (int m = 0; m < 8; ++m)
#pragma unroll
                for (int c = 0; c < 8; ++c)
                    acc[m][c] += ev[m]*wv[c];
        }
        __syncthreads();
    }
#pragma unroll
    for (int m = 0; m < 8; ++m) {
        int n = n0 + ty*8 + m;
        if (n < n_nodes) {
            *(float4*)&An[n*D + tx*4] = make_float4(acc[m][0],acc[m][1],acc[m][2],acc[m][3]);
            *(float4*)&Bn[n*D + tx*4] = make_float4(acc[m][4],acc[m][5],acc[m][6],acc[m][7]);
        }
    }
}

// ============ K1b: per-node attention scalars sA/sB = ent @ av1/av2 =============
__global__ void k1b_scalars(const float* __restrict__ ent, const float* __restrict__ av1,
                            const float* __restrict__ av2, float* __restrict__ sA,
                            float* __restrict__ sB, int n_nodes) {
    int g = threadIdx.x >> 5, lane = threadIdx.x & 31;
    int n = blockIdx.x*8 + g;
    if (n >= n_nodes) return;
    float4 e  = *(const float4*)&ent[n*D + lane*4];
    float4 v1 = *(const float4*)&av1[lane*4];
    float4 v2 = *(const float4*)&av2[lane*4];
    float p1 = e.x*v1.x + e.y*v1.y + e.z*v1.z + e.w*v1.w;
    float p2 = e.x*v2.x + e.y*v2.y + e.z*v2.z + e.w*v2.w;
    for (int m = 16; m > 0; m >>= 1) { p1 += __shfl_xor(p1, m, 32); p2 += __shfl_xor(p2, m, 32); }
    if (lane == 0) { sA[n] = p1; sB[n] = p2; }
}

// ============ K2: CSR build =============
__global__ void k_hist(const int* __restrict__ trip, int* __restrict__ deg, int n_edges) {
    int e = blockIdx.x*256 + threadIdx.x;
    if (e < n_edges) atomicAdd(&deg[trip[3*e]], 1);
}

__global__ void k_scan1(const int* __restrict__ deg, int* __restrict__ off,
                        int* __restrict__ bsum, int n) {
    __shared__ int s[1024];
    int i = blockIdx.x*1024 + threadIdx.x;
    int v = (i < n) ? deg[i] : 0;
    s[threadIdx.x] = v; __syncthreads();
    for (int d = 1; d < 1024; d <<= 1) {
        int t = (threadIdx.x >= d) ? s[threadIdx.x - d] : 0;
        __syncthreads();
        s[threadIdx.x] += t;
        __syncthreads();
    }
    if (i < n) off[i] = s[threadIdx.x] - v;          // exclusive, pre-block-offset
    if (threadIdx.x == 1023) bsum[blockIdx.x] = s[1023];
}

__global__ void k_scan2(int* __restrict__ bsum, int nb) {
    __shared__ int s[128];
    int v = (threadIdx.x < nb) ? bsum[threadIdx.x] : 0;
    s[threadIdx.x] = v; __syncthreads();
    for (int d = 1; d < 128; d <<= 1) {
        int t = (threadIdx.x >= d) ? s[threadIdx.x - d] : 0;
        __syncthreads();
        s[threadIdx.x] += t;
        __syncthreads();
    }
    if (threadIdx.x < nb) bsum[threadIdx.x] = s[threadIdx.x] - v;  // exclusive, in-place
}

__global__ void k_scan3(int* __restrict__ off, int* __restrict__ cursor,
                        const int* __restrict__ bsum, int n, int n_edges) {
    int i = blockIdx.x*1024 + threadIdx.x;
    if (i < n) {
        int o = off[i] + bsum[blockIdx.x];
        off[i] = o;
        cursor[i] = o;
    }
    if (i == 0) off[n] = n_edges;
}

// ============ K2c: per-edge b + scatter into CSR slots =============
__global__ void k_edge_b(const int* __restrict__ trip, const float* __restrict__ sA,
                         const float* __restrict__ sB, const float* __restrict__ sR,
                         const float* __restrict__ sConst, int* __restrict__ cursor,
                         int* __restrict__ key, float* __restrict__ bval, int n_edges) {
    int e = blockIdx.x*256 + threadIdx.x;
    if (e >= n_edges) return;
    int s = trip[3*e], d = trip[3*e+1], r = trip[3*e+2];
    float logit = sA[s] + sB[d] + sR[r] + sConst[0];
    float l = logit > 0.f ? logit : 0.01f*logit;
    float b = expf(l);
    int p = atomicAdd(&cursor[s], 1);
    key[p]  = d | (r << 20);
    bval[p] = b;
}

// ============ K3: node-major aggregation (no atomics) =============
// h[n] = A[n] + biasC + sum_e alpha_e * (B[dst_e] + R[rel_e]),  alpha_e = b_e / sum b
__global__ void k_aggregate(const int* __restrict__ off, const int* __restrict__ key,
                            const float* __restrict__ bval, const float* __restrict__ An,
                            const float* __restrict__ Bn, const float* __restrict__ Rm,
                            const float* __restrict__ biasC, float* __restrict__ h,
                            int n_nodes) {
    int g = threadIdx.x >> 5, lane = threadIdx.x & 31;
    int n = blockIdx.x*8 + g;
    if (n >= n_nodes) return;
    int o0 = off[n], o1 = off[n+1];
    int c = lane*4;
    if (o0 == o1) {
        *(float4*)&h[n*D + c] = make_float4(0.f,0.f,0.f,0.f);
        return;
    }
    float s = 0.f;
    for (int p = o0 + lane; p < o1; p += 32) s += bval[p];
    for (int m = 16; m > 0; m >>= 1) s += __shfl_xor(s, m, 32);
    float inv = 1.f / s;
    float4 acc = *(const float4*)&An[n*D + c];
    float4 bc  = *(const float4*)&biasC[c];
    acc.x += bc.x; acc.y += bc.y; acc.z += bc.z; acc.w += bc.w;
    for (int p = o0; p < o1; ++p) {
        int kd = key[p];
        float al = bval[p] * inv;
        int d = kd & 0xFFFFF;
        int r = kd >> 20;
        float4 bv = *(const float4*)&Bn[d*D + c];
        float4 rv = *(const float4*)&Rm[r*D + c];
        acc.x += al*(bv.x + rv.x);
        acc.y += al*(bv.y + rv.y);
        acc.z += al*(bv.z + rv.z);
        acc.w += al*(bv.w + rv.w);
    }
    *(float4*)&h[n*D + c] = acc;
}

extern "C" void kernel_launch(void* const* d_in, const int* in_sizes, int n_in,
                              void* d_out, int out_size, void* d_ws, size_t ws_size,
                              hipStream_t stream) {
    const int*   trip   = (const int*)  d_in[0];
    const float* ent    = (const float*)d_in[1];
    const float* relE   = (const float*)d_in[2];
    const float* W_ent  = (const float*)d_in[3];
    const float* b_ent  = (const float*)d_in[4];
    const float* W_rel  = (const float*)d_in[5];
    const float* b_rel  = (const float*)d_in[6];
    const float* W_ent2 = (const float*)d_in[7];
    const float* b_ent2 = (const float*)d_in[8];
    const float* a_w    = (const float*)d_in[9];
    const float* a_b    = (const float*)d_in[10];
    float* h = (float*)d_out;

    char* ws = (char*)d_ws;
    size_t o = 0;
    auto alloc = [&](size_t bytes) { size_t p = o; o += (bytes + 255) & ~(size_t)255; return p; };
    float* Wf     = (float*)(ws + alloc(128*256*4));
    float* WR     = (float*)(ws + alloc(128*128*4));
    float* biasC  = (float*)(ws + alloc(128*4));
    float* Rm     = (float*)(ws + alloc((size_t)N_RELS_C*128*4));
    float* av1    = (float*)(ws + alloc(128*4));
    float* av2    = (float*)(ws + alloc(128*4));
    float* sR     = (float*)(ws + alloc(N_RELS_C*4));
    float* sConst = (float*)(ws + alloc(4));
    float* sA     = (float*)(ws + alloc((size_t)N_NODES_C*4));
    float* sB     = (float*)(ws + alloc((size_t)N_NODES_C*4));
    int*   deg    = (int*)  (ws + alloc((size_t)N_NODES_C*4));
    int*   off    = (int*)  (ws + alloc(((size_t)N_NODES_C+1)*4));
    int*   cursor = (int*)  (ws + alloc((size_t)N_NODES_C*4));
    int*   bsum   = (int*)  (ws + alloc(128*4));
    int*   key    = (int*)  (ws + alloc((size_t)N_EDGES_C*4));
    float* bval   = (float*)(ws + alloc((size_t)N_EDGES_C*4));
    float* An     = (float*)(ws + alloc((size_t)N_NODES_C*128*4));
    float* Bn     = (float*)(ws + alloc((size_t)N_NODES_C*128*4));

    hipMemsetAsync(deg, 0, (size_t)N_NODES_C*4, stream);

    k_fuse_w<<<dim3(128,4), 128, 0, stream>>>(W_ent, W_rel, W_ent2, b_ent, b_rel, b_ent2,
                                              Wf, WR, biasC);
    k_rel_scalars<<<N_RELS_C+3, 128, 0, stream>>>(relE, a_w, a_b, Wf, WR, biasC,
                                                  Rm, av1, av2, sR, sConst);
    k1_gemm<<<(N_NODES_C+63)/64, 256, 0, stream>>>(ent, Wf, An, Bn, N_NODES_C);
    k1b_scalars<<<(N_NODES_C+7)/8, 256, 0, stream>>>(ent, av1, av2, sA, sB, N_NODES_C);
    k_hist<<<(N_EDGES_C+255)/256, 256, 0, stream>>>(trip, deg, N_EDGES_C);
    int nb = (N_NODES_C + 1023)/1024;   // 98
    k_scan1<<<nb, 1024, 0, stream>>>(deg, off, bsum, N_NODES_C);
    k_scan2<<<1, 128, 0, stream>>>(bsum, nb);
    k_scan3<<<nb, 1024, 0, stream>>>(off, cursor, bsum, N_NODES_C, N_EDGES_C);
    k_edge_b<<<(N_EDGES_C+255)/256, 256, 0, stream>>>(trip, sA, sB, sR, sConst,
                                                      cursor, key, bval, N_EDGES_C);
    k_aggregate<<<(N_NODES_C+7)/8, 256, 0, stream>>>(off, key, bval, An, Bn, Rm, biasC,
                                                     h, N_NODES_C);
}

// Round 2
// 276.597 us; speedup vs baseline: 1.2063x; 1.2063x over previous
//
#include <hip/hip_runtime.h>
#include <hip/hip_bf16.h>

#define N_NODES_C 100000
#define N_RELS_C  237
#define N_EDGES_C 500000
#define D 128

typedef __attribute__((ext_vector_type(8))) short short8;
typedef __attribute__((ext_vector_type(4))) float f32x4;

__device__ __forceinline__ ushort f2bf(float x) {
    union { float f; uint u; } v; v.f = x;
    uint r = v.u + 0x7FFFu + ((v.u >> 16) & 1u);   // RNE
    return (ushort)(r >> 16);
}
__device__ __forceinline__ float bf2f_hi(uint u) {  // bits already in high half
    union { uint u; float f; } v; v.u = u; return v.f;
}

// ============ K0: fuse weights =============
// Wf[k][j]      (j<128)  = sum_i W_ent[k][i] * W_ent2[i][j]        (-> A path)
// Wf[k][128+j]           = sum_i W_ent[k][i] * W_ent2[128+i][j]    (-> B path)
// WR[k][j]               = sum_i W_rel[k][i] * W_ent2[256+i][j]    (-> R path)
// Also emits WfTb: bf16, transposed [n][k] (n in 0..255), for the MFMA GEMM.
// biasC[j] = b_ent@(W1+W2) + b_rel@W3 + b_ent2
__global__ void k_fuse_w(const float* __restrict__ W_ent, const float* __restrict__ W_rel,
                         const float* __restrict__ W_ent2,
                         const float* __restrict__ b_ent, const float* __restrict__ b_rel,
                         const float* __restrict__ b_ent2,
                         float* __restrict__ Wf, float* __restrict__ WR,
                         ushort* __restrict__ WfTb, float* __restrict__ biasC) {
    int j = threadIdx.x;       // 0..127 output col
    int k = blockIdx.x;        // 0..127 row
    int which = blockIdx.y;    // 0..3
    if (which == 0) {
        float acc = 0.f;
        for (int i = 0; i < D; ++i) acc += W_ent[k*D+i] * W_ent2[i*D+j];
        Wf[k*256 + j] = acc;
        WfTb[j*D + k] = f2bf(acc);
    } else if (which == 1) {
        float acc = 0.f;
        for (int i = 0; i < D; ++i) acc += W_ent[k*D+i] * W_ent2[(D+i)*D+j];
        Wf[k*256 + D + j] = acc;
        WfTb[(D+j)*D + k] = f2bf(acc);
    } else if (which == 2) {
        float acc = 0.f;
        for (int i = 0; i < D; ++i) acc += W_rel[k*D+i] * W_ent2[(2*D+i)*D+j];
        WR[k*D + j] = acc;
    } else if (k == 0) {
        float acc = b_ent2[j];
        for (int i = 0; i < D; ++i) {
            acc += b_ent[i] * (W_ent2[i*D+j] + W_ent2[(D+i)*D+j]);
            acc += b_rel[i] * W_ent2[(2*D+i)*D+j];
        }
        biasC[j] = acc;
    }
}

// ============ K0b: relation table + attention scalars =============
__global__ void k_rel_scalars(const float* __restrict__ rel_embed,
                              const float* __restrict__ a_w, const float* __restrict__ a_b,
                              const float* __restrict__ Wf, const float* __restrict__ WR,
                              const float* __restrict__ biasC,
                              float* __restrict__ Rm, float* __restrict__ av1,
                              float* __restrict__ av2, float* __restrict__ sR,
                              float* __restrict__ sConst) {
    int j = threadIdx.x;   // 128 threads
    int b = blockIdx.x;    // 0..239
    __shared__ float red[128];
    if (b < N_RELS_C) {
        float acc = 0.f;
        for (int k = 0; k < D; ++k) acc += rel_embed[b*D+k] * WR[k*D+j];
        Rm[b*D+j] = acc;
        red[j] = acc * a_w[j];
        __syncthreads();
        for (int s = 64; s > 0; s >>= 1) { if (j < s) red[j] += red[j+s]; __syncthreads(); }
        if (j == 0) sR[b] = red[0];
    } else if (b == N_RELS_C) {
        float acc = 0.f;
        for (int t = 0; t < D; ++t) acc += Wf[j*256 + t] * a_w[t];
        av1[j] = acc;
    } else if (b == N_RELS_C + 1) {
        float acc = 0.f;
        for (int t = 0; t < D; ++t) acc += Wf[j*256 + D + t] * a_w[t];
        av2[j] = acc;
    } else {
        red[j] = biasC[j] * a_w[j];
        __syncthreads();
        for (int s = 64; s > 0; s >>= 1) { if (j < s) red[j] += red[j+s]; __syncthreads(); }
        if (j == 0) sConst[0] = red[0] + a_b[0];
    }
}

// ============ K1: MFMA node GEMM =============
// [An | Bn] = ent(100000x128) @ Wf(128x256), bf16 inputs, fp32 accumulate.
// Grid (ceil(M/128), 2): blockIdx.y picks the N-half (0 -> An fp32, 1 -> Bn bf16).
// LDS: ent tile 128x128 bf16 + WfT tile 128x128 bf16, XOR-swizzled 16B units
// (conflict-free ds_read_b128 fragment loads), exactly 64 KB -> 2 blocks/CU.
__global__ __launch_bounds__(256) void k1_mfma(const float* __restrict__ ent,
                                               const ushort* __restrict__ WfTb,
                                               float* __restrict__ An,
                                               ushort* __restrict__ Bn,
                                               int n_nodes) {
    __shared__ __align__(16) ushort entL[128*128];
    __shared__ __align__(16) ushort wL[128*128];
    int tid = threadIdx.x;
    int m0 = blockIdx.x * 128;
    int ny = blockIdx.y;
    const ushort* wsrc = WfTb + ny * 128 * D;

    // stage W half: 128 n-rows x 128 k (bf16, global row-major [n][k])
#pragma unroll
    for (int u = 0; u < 8; ++u) {
        int f = u*256 + tid;          // 16B-unit index, 2048 units
        int r = f >> 4, k16 = f & 15;
        *(uint4*)&wL[r*128 + ((k16 ^ (r & 15)) << 3)] =
            *(const uint4*)&wsrc[r*128 + (k16 << 3)];
    }
    // stage ent tile: fp32 global -> bf16 LDS, same swizzle
#pragma unroll
    for (int u = 0; u < 8; ++u) {
        int f = u*256 + tid;
        int r = f >> 4, k16 = f & 15;
        int n = m0 + r;
        float4 e0 = make_float4(0.f,0.f,0.f,0.f), e1 = e0;
        if (n < n_nodes) {
            e0 = *(const float4*)&ent[(size_t)n*D + (k16 << 3)];
            e1 = *(const float4*)&ent[(size_t)n*D + (k16 << 3) + 4];
        }
        short8 pk;
        pk[0]=(short)f2bf(e0.x); pk[1]=(short)f2bf(e0.y); pk[2]=(short)f2bf(e0.z); pk[3]=(short)f2bf(e0.w);
        pk[4]=(short)f2bf(e1.x); pk[5]=(short)f2bf(e1.y); pk[6]=(short)f2bf(e1.z); pk[7]=(short)f2bf(e1.w);
        *(short8*)&entL[r*128 + ((k16 ^ (r & 15)) << 3)] = pk;
    }
    __syncthreads();

    int wave = tid >> 6, lane = tid & 63;
    int q = lane >> 4, c = lane & 15;
    int wm = (wave >> 1) * 64, wn = (wave & 1) * 64;

    f32x4 acc[4][4];
#pragma unroll
    for (int mt = 0; mt < 4; ++mt)
#pragma unroll
        for (int nt = 0; nt < 4; ++nt) { f32x4 z = {0.f,0.f,0.f,0.f}; acc[mt][nt] = z; }

#pragma unroll
    for (int chunk = 0; chunk < 4; ++chunk) {
        int k16 = chunk*4 + q;
        short8 a[4], b[4];
#pragma unroll
        for (int mt = 0; mt < 4; ++mt) {
            int row = wm + mt*16 + c;
            a[mt] = *(const short8*)&entL[row*128 + ((k16 ^ (row & 15)) << 3)];
        }
#pragma unroll
        for (int nt = 0; nt < 4; ++nt) {
            int row = wn + nt*16 + c;
            b[nt] = *(const short8*)&wL[row*128 + ((k16 ^ (row & 15)) << 3)];
        }
#pragma unroll
        for (int mt = 0; mt < 4; ++mt)
#pragma unroll
            for (int nt = 0; nt < 4; ++nt)
                acc[mt][nt] = __builtin_amdgcn_mfma_f32_16x16x32_bf16(a[mt], b[nt], acc[mt][nt], 0, 0, 0);
    }

    // epilogue: C/D layout col=lane&15, row=quad*4+reg
#pragma unroll
    for (int mt = 0; mt < 4; ++mt) {
#pragma unroll
        for (int reg = 0; reg < 4; ++reg) {
            int m = m0 + wm + mt*16 + q*4 + reg;
            if (m < n_nodes) {
#pragma unroll
                for (int nt = 0; nt < 4; ++nt) {
                    int col = wn + nt*16 + c;
                    float v = acc[mt][nt][reg];
                    if (ny == 0) An[(size_t)m*D + col] = v;
                    else         Bn[(size_t)m*D + col] = f2bf(v);
                }
            }
        }
    }
}

// ============ K1b: per-node attention scalars sA/sB = ent @ av1/av2 =============
__global__ void k1b_scalars(const float* __restrict__ ent, const float* __restrict__ av1,
                            const float* __restrict__ av2, float* __restrict__ sA,
                            float* __restrict__ sB, int n_nodes) {
    int g = threadIdx.x >> 5, lane = threadIdx.x & 31;
    int n = blockIdx.x*8 + g;
    if (n >= n_nodes) return;
    float4 e  = *(const float4*)&ent[(size_t)n*D + lane*4];
    float4 v1 = *(const float4*)&av1[lane*4];
    float4 v2 = *(const float4*)&av2[lane*4];
    float p1 = e.x*v1.x + e.y*v1.y + e.z*v1.z + e.w*v1.w;
    float p2 = e.x*v2.x + e.y*v2.y + e.z*v2.z + e.w*v2.w;
    for (int m = 16; m > 0; m >>= 1) { p1 += __shfl_xor(p1, m, 32); p2 += __shfl_xor(p2, m, 32); }
    if (lane == 0) { sA[n] = p1; sB[n] = p2; }
}

// ============ K2: CSR build =============
__global__ void k_hist(const int* __restrict__ trip, int* __restrict__ deg, int n_edges) {
    int e = blockIdx.x*256 + threadIdx.x;
    if (e < n_edges) atomicAdd(&deg[trip[3*e]], 1);
}

__global__ void k_scan1(const int* __restrict__ deg, int* __restrict__ off,
                        int* __restrict__ bsum, int n) {
    __shared__ int s[1024];
    int i = blockIdx.x*1024 + threadIdx.x;
    int v = (i < n) ? deg[i] : 0;
    s[threadIdx.x] = v; __syncthreads();
    for (int d = 1; d < 1024; d <<= 1) {
        int t = (threadIdx.x >= d) ? s[threadIdx.x - d] : 0;
        __syncthreads();
        s[threadIdx.x] += t;
        __syncthreads();
    }
    if (i < n) off[i] = s[threadIdx.x] - v;
    if (threadIdx.x == 1023) bsum[blockIdx.x] = s[1023];
}

__global__ void k_scan2(int* __restrict__ bsum, int nb) {
    __shared__ int s[128];
    int v = (threadIdx.x < nb) ? bsum[threadIdx.x] : 0;
    s[threadIdx.x] = v; __syncthreads();
    for (int d = 1; d < 128; d <<= 1) {
        int t = (threadIdx.x >= d) ? s[threadIdx.x - d] : 0;
        __syncthreads();
        s[threadIdx.x] += t;
        __syncthreads();
    }
    if (threadIdx.x < nb) bsum[threadIdx.x] = s[threadIdx.x] - v;
}

__global__ void k_scan3(int* __restrict__ off, int* __restrict__ cursor,
                        const int* __restrict__ bsum, int n, int n_edges) {
    int i = blockIdx.x*1024 + threadIdx.x;
    if (i < n) {
        int o = off[i] + bsum[blockIdx.x];
        off[i] = o;
        cursor[i] = o;
    }
    if (i == 0) off[n] = n_edges;
}

// ============ K2c: per-edge b + scatter into CSR slots =============
__global__ void k_edge_b(const int* __restrict__ trip, const float* __restrict__ sA,
                         const float* __restrict__ sB, const float* __restrict__ sR,
                         const float* __restrict__ sConst, int* __restrict__ cursor,
                         int* __restrict__ key, float* __restrict__ bval, int n_edges) {
    int e = blockIdx.x*256 + threadIdx.x;
    if (e >= n_edges) return;
    int s = trip[3*e], d = trip[3*e+1], r = trip[3*e+2];
    float logit = sA[s] + sB[d] + sR[r] + sConst[0];
    float l = logit > 0.f ? logit : 0.01f*logit;
    float b = expf(l);
    int p = atomicAdd(&cursor[s], 1);
    key[p]  = d | (r << 20);
    bval[p] = b;
}

// ============ K3: node-major aggregation (no atomics), Bn in bf16 =============
__global__ void k_aggregate(const int* __restrict__ off, const int* __restrict__ key,
                            const float* __restrict__ bval, const float* __restrict__ An,
                            const ushort* __restrict__ Bn, const float* __restrict__ Rm,
                            const float* __restrict__ biasC, float* __restrict__ h,
                            int n_nodes) {
    int g = threadIdx.x >> 5, lane = threadIdx.x & 31;
    int n = blockIdx.x*8 + g;
    if (n >= n_nodes) return;
    int o0 = off[n], o1 = off[n+1];
    int c = lane*4;
    if (o0 == o1) {
        *(float4*)&h[(size_t)n*D + c] = make_float4(0.f,0.f,0.f,0.f);
        return;
    }
    float s = 0.f;
    for (int p = o0 + lane; p < o1; p += 32) s += bval[p];
    for (int m = 16; m > 0; m >>= 1) s += __shfl_xor(s, m, 32);
    float inv = 1.f / s;
    float4 acc = *(const float4*)&An[(size_t)n*D + c];
    float4 bc  = *(const float4*)&biasC[c];
    acc.x += bc.x; acc.y += bc.y; acc.z += bc.z; acc.w += bc.w;
    for (int p = o0; p < o1; ++p) {
        int kd = key[p];
        float al = bval[p] * inv;
        int d = kd & 0xFFFFF;
        int r = kd >> 20;
        uint2 braw = *(const uint2*)&Bn[(size_t)d*D + c];
        float4 rv  = *(const float4*)&Rm[r*D + c];
        float b0 = bf2f_hi(braw.x << 16), b1 = bf2f_hi(braw.x & 0xFFFF0000u);
        float b2 = bf2f_hi(braw.y << 16), b3 = bf2f_hi(braw.y & 0xFFFF0000u);
        acc.x += al*(b0 + rv.x);
        acc.y += al*(b1 + rv.y);
        acc.z += al*(b2 + rv.z);
        acc.w += al*(b3 + rv.w);
    }
    *(float4*)&h[(size_t)n*D + c] = acc;
}

extern "C" void kernel_launch(void* const* d_in, const int* in_sizes, int n_in,
                              void* d_out, int out_size, void* d_ws, size_t ws_size,
                              hipStream_t stream) {
    const int*   trip   = (const int*)  d_in[0];
    const float* ent    = (const float*)d_in[1];
    const float* relE   = (const float*)d_in[2];
    const float* W_ent  = (const float*)d_in[3];
    const float* b_ent  = (const float*)d_in[4];
    const float* W_rel  = (const float*)d_in[5];
    const float* b_rel  = (const float*)d_in[6];
    const float* W_ent2 = (const float*)d_in[7];
    const float* b_ent2 = (const float*)d_in[8];
    const float* a_w    = (const float*)d_in[9];
    const float* a_b    = (const float*)d_in[10];
    float* h = (float*)d_out;

    char* ws = (char*)d_ws;
    size_t o = 0;
    auto alloc = [&](size_t bytes) { size_t p = o; o += (bytes + 255) & ~(size_t)255; return p; };
    float*  Wf     = (float*) (ws + alloc(128*256*4));
    float*  WR     = (float*) (ws + alloc(128*128*4));
    ushort* WfTb   = (ushort*)(ws + alloc(256*128*2));
    float*  biasC  = (float*) (ws + alloc(128*4));
    float*  Rm     = (float*) (ws + alloc((size_t)N_RELS_C*128*4));
    float*  av1    = (float*) (ws + alloc(128*4));
    float*  av2    = (float*) (ws + alloc(128*4));
    float*  sR     = (float*) (ws + alloc(N_RELS_C*4));
    float*  sConst = (float*) (ws + alloc(4));
    float*  sA     = (float*) (ws + alloc((size_t)N_NODES_C*4));
    float*  sB     = (float*) (ws + alloc((size_t)N_NODES_C*4));
    int*    deg    = (int*)   (ws + alloc((size_t)N_NODES_C*4));
    int*    off    = (int*)   (ws + alloc(((size_t)N_NODES_C+1)*4));
    int*    cursor = (int*)   (ws + alloc((size_t)N_NODES_C*4));
    int*    bsum   = (int*)   (ws + alloc(128*4));
    int*    key    = (int*)   (ws + alloc((size_t)N_EDGES_C*4));
    float*  bval   = (float*) (ws + alloc((size_t)N_EDGES_C*4));
    float*  An     = (float*) (ws + alloc((size_t)N_NODES_C*128*4));
    ushort* Bn     = (ushort*)(ws + alloc((size_t)N_NODES_C*128*2));

    hipMemsetAsync(deg, 0, (size_t)N_NODES_C*4, stream);

    k_fuse_w<<<dim3(128,4), 128, 0, stream>>>(W_ent, W_rel, W_ent2, b_ent, b_rel, b_ent2,
                                              Wf, WR, WfTb, biasC);
    k_rel_scalars<<<N_RELS_C+3, 128, 0, stream>>>(relE, a_w, a_b, Wf, WR, biasC,
                                                  Rm, av1, av2, sR, sConst);
    k1_mfma<<<dim3((N_NODES_C+127)/128, 2), 256, 0, stream>>>(ent, WfTb, An, Bn, N_NODES_C);
    k1b_scalars<<<(N_NODES_C+7)/8, 256, 0, stream>>>(ent, av1, av2, sA, sB, N_NODES_C);
    k_hist<<<(N_EDGES_C+255)/256, 256, 0, stream>>>(trip, deg, N_EDGES_C);
    int nb = (N_NODES_C + 1023)/1024;   // 98
    k_scan1<<<nb, 1024, 0, stream>>>(deg, off, bsum, N_NODES_C);
    k_scan2<<<1, 128, 0, stream>>>(bsum, nb);
    k_scan3<<<nb, 1024, 0, stream>>>(off, cursor, bsum, N_NODES_C, N_EDGES_C);
    k_edge_b<<<(N_EDGES_C+255)/256, 256, 0, stream>>>(trip, sA, sB, sR, sConst,
                                                      cursor, key, bval, N_EDGES_C);
    k_aggregate<<<(N_NODES_C+7)/8, 256, 0, stream>>>(off, key, bval, An, Bn, Rm, biasC,
                                                     h, N_NODES_C);
}

// Round 4
// 267.839 us; speedup vs baseline: 1.2457x; 1.0327x over previous
//
#include <hip/hip_runtime.h>
#include <hip/hip_bf16.h>

#define N_NODES_C 100000
#define N_PAD_C   100096   // padded to multiple of 128 for k1 tiles
#define N_RELS_C  237
#define N_EDGES_C 500000
#define D 128

typedef __attribute__((ext_vector_type(8))) short short8;
typedef __attribute__((ext_vector_type(4))) float f32x4;

__device__ __forceinline__ ushort f2bf(float x) {
    union { float f; uint u; } v; v.f = x;
    uint r = v.u + 0x7FFFu + ((v.u >> 16) & 1u);   // RNE
    return (ushort)(r >> 16);
}
__device__ __forceinline__ float bf2f_hi(uint u) {  // bits already in high half
    union { uint u; float f; } v; v.u = u; return v.f;
}

// ============ K0: fuse weights =============
// Wf[k][j] (j<128) = W_ent@W1 ; Wf[k][128+j] = W_ent@W2 ; WR = W_rel@W3
// WfTb: bf16, transposed [n][k] (n in 0..255) for MFMA B-operand.
// biasC[j] = b_ent@(W1+W2) + b_rel@W3 + b_ent2
__global__ void k_fuse_w(const float* __restrict__ W_ent, const float* __restrict__ W_rel,
                         const float* __restrict__ W_ent2,
                         const float* __restrict__ b_ent, const float* __restrict__ b_rel,
                         const float* __restrict__ b_ent2,
                         float* __restrict__ Wf, float* __restrict__ WR,
                         ushort* __restrict__ WfTb, float* __restrict__ biasC) {
    int j = threadIdx.x;       // 0..127 output col
    int k = blockIdx.x;        // 0..127 row
    int which = blockIdx.y;    // 0..3
    if (which == 0) {
        float acc = 0.f;
        for (int i = 0; i < D; ++i) acc += W_ent[k*D+i] * W_ent2[i*D+j];
        Wf[k*256 + j] = acc;
        WfTb[j*D + k] = f2bf(acc);
    } else if (which == 1) {
        float acc = 0.f;
        for (int i = 0; i < D; ++i) acc += W_ent[k*D+i] * W_ent2[(D+i)*D+j];
        Wf[k*256 + D + j] = acc;
        WfTb[(D+j)*D + k] = f2bf(acc);
    } else if (which == 2) {
        float acc = 0.f;
        for (int i = 0; i < D; ++i) acc += W_rel[k*D+i] * W_ent2[(2*D+i)*D+j];
        WR[k*D + j] = acc;
    } else if (k == 0) {
        float acc = b_ent2[j];
        for (int i = 0; i < D; ++i) {
            acc += b_ent[i] * (W_ent2[i*D+j] + W_ent2[(D+i)*D+j]);
            acc += b_rel[i] * W_ent2[(2*D+i)*D+j];
        }
        biasC[j] = acc;
    }
}

// ============ K0b: relation table + attention scalars =============
__global__ void k_rel_scalars(const float* __restrict__ rel_embed,
                              const float* __restrict__ a_w, const float* __restrict__ a_b,
                              const float* __restrict__ Wf, const float* __restrict__ WR,
                              const float* __restrict__ biasC,
                              float* __restrict__ Rm, float* __restrict__ av1,
                              float* __restrict__ av2, float* __restrict__ sR,
                              float* __restrict__ sConst) {
    int j = threadIdx.x;   // 128 threads
    int b = blockIdx.x;    // 0..239
    __shared__ float red[128];
    if (b < N_RELS_C) {
        float acc = 0.f;
        for (int k = 0; k < D; ++k) acc += rel_embed[b*D+k] * WR[k*D+j];
        Rm[b*D+j] = acc;
        red[j] = acc * a_w[j];
        __syncthreads();
        for (int s = 64; s > 0; s >>= 1) { if (j < s) red[j] += red[j+s]; __syncthreads(); }
        if (j == 0) sR[b] = red[0];
    } else if (b == N_RELS_C) {
        float acc = 0.f;
        for (int t = 0; t < D; ++t) acc += Wf[j*256 + t] * a_w[t];
        av1[j] = acc;
    } else if (b == N_RELS_C + 1) {
        float acc = 0.f;
        for (int t = 0; t < D; ++t) acc += Wf[j*256 + D + t] * a_w[t];
        av2[j] = acc;
    } else {
        red[j] = biasC[j] * a_w[j];
        __syncthreads();
        for (int s = 64; s > 0; s >>= 1) { if (j < s) red[j] += red[j+s]; __syncthreads(); }
        if (j == 0) sConst[0] = red[0] + a_b[0];
    }
}

// ============ K_prep: ent fp32 -> entB bf16 (padded) + sA/sB scalars in one pass ======
__global__ void k_prep(const float* __restrict__ ent, const float* __restrict__ av1,
                       const float* __restrict__ av2, ushort* __restrict__ entB,
                       float* __restrict__ sA, float* __restrict__ sB,
                       int n_nodes, int n_pad) {
    int g = threadIdx.x >> 5, lane = threadIdx.x & 31;
    int n = blockIdx.x*8 + g;
    if (n >= n_pad) return;
    if (n >= n_nodes) {
        ushort4 z = {0,0,0,0};
        *(ushort4*)&entB[(size_t)n*D + lane*4] = z;
        return;
    }
    float4 e  = *(const float4*)&ent[(size_t)n*D + lane*4];
    ushort4 pk;
    pk.x = f2bf(e.x); pk.y = f2bf(e.y); pk.z = f2bf(e.z); pk.w = f2bf(e.w);
    *(ushort4*)&entB[(size_t)n*D + lane*4] = pk;
    float4 v1 = *(const float4*)&av1[lane*4];
    float4 v2 = *(const float4*)&av2[lane*4];
    float p1 = e.x*v1.x + e.y*v1.y + e.z*v1.z + e.w*v1.w;
    float p2 = e.x*v2.x + e.y*v2.y + e.z*v2.z + e.w*v2.w;
    for (int m = 16; m > 0; m >>= 1) { p1 += __shfl_xor(p1, m, 32); p2 += __shfl_xor(p2, m, 32); }
    if (lane == 0) { sA[n] = p1; sB[n] = p2; }
}

// ============ K1: MFMA node GEMM =============
// [An|Bn] = entB(100096x128 bf16) @ WfT(256x128 bf16), fp32 accumulate.
// A-half (cols 0..127) is stored fp32 DIRECTLY INTO h (d_out) — it is the
// additive per-node term of the output; k_aggregate later reads-modifies-writes.
// B-half stored bf16 into BnB. LDS holds only W (64 KB, XOR-swizzled); A-frags
// stream from global entB. Single __syncthreads after W staging.
__global__ __launch_bounds__(256) void k1_mfma(const ushort* __restrict__ entB,
                                               const ushort* __restrict__ WfTb,
                                               float* __restrict__ h,
                                               ushort* __restrict__ BnB,
                                               int n_nodes) {
    __shared__ __align__(16) ushort wL[256*128];   // 64 KB
    int tid = threadIdx.x;
    int m0 = blockIdx.x * 128;

    // stage W: 256 rows x 16 (16B units), swizzled unit col = k16 ^ (r&15)
#pragma unroll
    for (int u = 0; u < 16; ++u) {
        int f = u*256 + tid;          // 0..4095
        int r = f >> 4, k16 = f & 15;
        *(uint4*)&wL[r*128 + ((k16 ^ (r & 15)) << 3)] =
            *(const uint4*)&WfTb[r*128 + (k16 << 3)];
    }
    __syncthreads();

    int wave = tid >> 6, lane = tid & 63;
    int q = lane >> 4, c = lane & 15;
    int wm = wave * 32;                 // 4 waves x 32 rows = 128 rows

    f32x4 acc[2][16];
#pragma unroll
    for (int mt = 0; mt < 2; ++mt)
#pragma unroll
        for (int nt = 0; nt < 16; ++nt) { f32x4 z = {0.f,0.f,0.f,0.f}; acc[mt][nt] = z; }

#pragma unroll
    for (int chunk = 0; chunk < 4; ++chunk) {
        int k16 = chunk*4 + q;
        short8 a[2];
#pragma unroll
        for (int mt = 0; mt < 2; ++mt)
            a[mt] = *(const short8*)&entB[(size_t)(m0 + wm + mt*16 + c)*D + (k16 << 3)];
#pragma unroll
        for (int nt = 0; nt < 16; ++nt) {
            int row = nt*16 + c;
            short8 b = *(const short8*)&wL[row*128 + ((k16 ^ c) << 3)];
            acc[0][nt] = __builtin_amdgcn_mfma_f32_16x16x32_bf16(a[0], b, acc[0][nt], 0, 0, 0);
            acc[1][nt] = __builtin_amdgcn_mfma_f32_16x16x32_bf16(a[1], b, acc[1][nt], 0, 0, 0);
        }
    }

    // epilogue: C/D layout col=lane&15, row=q*4+reg
#pragma unroll
    for (int mt = 0; mt < 2; ++mt) {
#pragma unroll
        for (int reg = 0; reg < 4; ++reg) {
            int m = m0 + wm + mt*16 + q*4 + reg;
            if (m < n_nodes) {
#pragma unroll
                for (int nt = 0; nt < 16; ++nt) {
                    int col = nt*16 + c;
                    float v = acc[mt][nt][reg];
                    if (col < D) h[(size_t)m*D + col] = v;
                    else         BnB[(size_t)m*D + (col - D)] = f2bf(v);
                }
            }
        }
    }
}

// ============ K2: CSR build =============
__global__ void k_hist(const int* __restrict__ trip, int* __restrict__ deg, int n_edges) {
    int e = blockIdx.x*256 + threadIdx.x;
    if (e >= n_edges) return;
    int s = trip[3*e], d = trip[3*e+1], r = trip[3*e+2];
    if ((unsigned)s >= (unsigned)N_NODES_C || (unsigned)d >= (unsigned)N_NODES_C ||
        (unsigned)r >= (unsigned)N_RELS_C) return;   // guard (no-op on valid input)
    atomicAdd(&deg[s], 1);
}

__global__ void k_scan1(const int* __restrict__ deg, int* __restrict__ off,
                        int* __restrict__ bsum, int n) {
    __shared__ int s[1024];
    int i = blockIdx.x*1024 + threadIdx.x;
    int v = (i < n) ? deg[i] : 0;
    s[threadIdx.x] = v; __syncthreads();
    for (int d = 1; d < 1024; d <<= 1) {
        int t = (threadIdx.x >= d) ? s[threadIdx.x - d] : 0;
        __syncthreads();
        s[threadIdx.x] += t;
        __syncthreads();
    }
    if (i < n) off[i] = s[threadIdx.x] - v;
    if (threadIdx.x == 1023) bsum[blockIdx.x] = s[1023];
}

__global__ void k_scan2(int* __restrict__ bsum, int nb) {
    __shared__ int s[128];
    int v = (threadIdx.x < nb) ? bsum[threadIdx.x] : 0;
    s[threadIdx.x] = v; __syncthreads();
    for (int d = 1; d < 128; d <<= 1) {
        int t = (threadIdx.x >= d) ? s[threadIdx.x - d] : 0;
        __syncthreads();
        s[threadIdx.x] += t;
        __syncthreads();
    }
    if (threadIdx.x < nb) bsum[threadIdx.x] = s[threadIdx.x] - v;
}

__global__ void k_scan3(int* __restrict__ off, int* __restrict__ cursor,
                        const int* __restrict__ bsum, int n, int total_edges) {
    int i = blockIdx.x*1024 + threadIdx.x;
    if (i < n) {
        int o = off[i] + bsum[blockIdx.x];
        off[i] = o;
        cursor[i] = o;
    }
    if (i == 0) off[n] = total_edges;
}

// ============ K2c: per-edge b + scatter into CSR slots =============
__global__ void k_edge_b(const int* __restrict__ trip, const float* __restrict__ sA,
                         const float* __restrict__ sB, const float* __restrict__ sR,
                         const float* __restrict__ sConst, int* __restrict__ cursor,
                         int* __restrict__ key, float* __restrict__ bval, int n_edges) {
    int e = blockIdx.x*256 + threadIdx.x;
    if (e >= n_edges) return;
    int s = trip[3*e], d = trip[3*e+1], r = trip[3*e+2];
    if ((unsigned)s >= (unsigned)N_NODES_C || (unsigned)d >= (unsigned)N_NODES_C ||
        (unsigned)r >= (unsigned)N_RELS_C) return;   // guard (matches k_hist)
    float logit = sA[s] + sB[d] + sR[r] + sConst[0];
    float l = logit > 0.f ? logit : 0.01f*logit;
    float b = expf(l);
    int p = atomicAdd(&cursor[s], 1);
    key[p]  = d | (r << 20);
    bval[p] = b;
}

// ============ K3: node-major aggregation (no atomics) =============
// h already holds An (fp32). h[n] = An + biasC + sum alpha*(B[dst]+R[rel]);
// zero-degree nodes overwritten with 0 (segment_sum over empty set).
__global__ void k_aggregate(const int* __restrict__ off, const int* __restrict__ key,
                            const float* __restrict__ bval, const ushort* __restrict__ BnB,
                            const float* __restrict__ Rm, const float* __restrict__ biasC,
                            float* __restrict__ h, int n_nodes) {
    int g = threadIdx.x >> 5, lane = threadIdx.x & 31;
    int n = blockIdx.x*8 + g;
    if (n >= n_nodes) return;
    int o0 = off[n], o1 = off[n+1];
    int c = lane*4;
    if (o0 == o1) {
        *(float4*)&h[(size_t)n*D + c] = make_float4(0.f,0.f,0.f,0.f);
        return;
    }
    float s = 0.f;
    for (int p = o0 + lane; p < o1; p += 32) s += bval[p];
    for (int m = 16; m > 0; m >>= 1) s += __shfl_xor(s, m, 32);
    float inv = 1.f / s;
    float4 acc = *(const float4*)&h[(size_t)n*D + c];     // An (fp32)
    float4 bc  = *(const float4*)&biasC[c];
    acc.x += bc.x; acc.y += bc.y; acc.z += bc.z; acc.w += bc.w;
    for (int p = o0; p < o1; ++p) {
        int kd = key[p];
        float al = bval[p] * inv;
        int d = kd & 0xFFFFF;
        int r = kd >> 20;
        uint2 braw = *(const uint2*)&BnB[(size_t)d*D + c];
        float4 rv  = *(const float4*)&Rm[r*D + c];
        float b0 = bf2f_hi(braw.x << 16), b1 = bf2f_hi(braw.x & 0xFFFF0000u);
        float b2 = bf2f_hi(braw.y << 16), b3 = bf2f_hi(braw.y & 0xFFFF0000u);
        acc.x += al*(b0 + rv.x);
        acc.y += al*(b1 + rv.y);
        acc.z += al*(b2 + rv.z);
        acc.w += al*(b3 + rv.w);
    }
    *(float4*)&h[(size_t)n*D + c] = acc;
}

extern "C" void kernel_launch(void* const* d_in, const int* in_sizes, int n_in,
                              void* d_out, int out_size, void* d_ws, size_t ws_size,
                              hipStream_t stream) {
    const int*   trip   = (const int*)  d_in[0];
    const float* ent    = (const float*)d_in[1];
    const float* relE   = (const float*)d_in[2];
    const float* W_ent  = (const float*)d_in[3];
    const float* b_ent  = (const float*)d_in[4];
    const float* W_rel  = (const float*)d_in[5];
    const float* b_rel  = (const float*)d_in[6];
    const float* W_ent2 = (const float*)d_in[7];
    const float* b_ent2 = (const float*)d_in[8];
    const float* a_w    = (const float*)d_in[9];
    const float* a_b    = (const float*)d_in[10];
    float* h = (float*)d_out;

    // Workspace: 57.6 MB total (well under the 83.19 MB footprint proven safe
    // in round 2 — round 3's 83.26 MB tail overran d_ws and corrupted adjacent
    // harness allocations, poisoning later calls).
    char* ws = (char*)d_ws;
    size_t o = 0;
    auto alloc = [&](size_t bytes) { size_t p = o; o += (bytes + 255) & ~(size_t)255; return p; };
    float*  Wf     = (float*) (ws + alloc(128*256*4));
    float*  WR     = (float*) (ws + alloc(128*128*4));
    ushort* WfTb   = (ushort*)(ws + alloc(256*128*2));
    float*  biasC  = (float*) (ws + alloc(128*4));
    float*  Rm     = (float*) (ws + alloc((size_t)N_RELS_C*128*4));
    float*  av1    = (float*) (ws + alloc(128*4));
    float*  av2    = (float*) (ws + alloc(128*4));
    float*  sR     = (float*) (ws + alloc(N_RELS_C*4));
    float*  sConst = (float*) (ws + alloc(4));
    float*  sA     = (float*) (ws + alloc((size_t)N_NODES_C*4));
    float*  sB     = (float*) (ws + alloc((size_t)N_NODES_C*4));
    int*    deg    = (int*)   (ws + alloc((size_t)N_NODES_C*4));
    int*    off    = (int*)   (ws + alloc(((size_t)N_NODES_C+1)*4));
    int*    cursor = (int*)   (ws + alloc((size_t)N_NODES_C*4));
    int*    bsum   = (int*)   (ws + alloc(128*4));
    int*    key    = (int*)   (ws + alloc((size_t)N_EDGES_C*4));
    float*  bval   = (float*) (ws + alloc((size_t)N_EDGES_C*4));
    ushort* entB   = (ushort*)(ws + alloc((size_t)N_PAD_C*128*2));
    ushort* BnB    = (ushort*)(ws + alloc((size_t)N_PAD_C*128*2));

    hipMemsetAsync(deg, 0, (size_t)N_NODES_C*4, stream);

    k_fuse_w<<<dim3(128,4), 128, 0, stream>>>(W_ent, W_rel, W_ent2, b_ent, b_rel, b_ent2,
                                              Wf, WR, WfTb, biasC);
    k_rel_scalars<<<N_RELS_C+3, 128, 0, stream>>>(relE, a_w, a_b, Wf, WR, biasC,
                                                  Rm, av1, av2, sR, sConst);
    k_prep<<<N_PAD_C/8, 256, 0, stream>>>(ent, av1, av2, entB, sA, sB, N_NODES_C, N_PAD_C);
    k1_mfma<<<N_PAD_C/128, 256, 0, stream>>>(entB, WfTb, h, BnB, N_NODES_C);
    k_hist<<<(N_EDGES_C+255)/256, 256, 0, stream>>>(trip, deg, N_EDGES_C);
    int nb = (N_NODES_C + 1023)/1024;   // 98
    k_scan1<<<nb, 1024, 0, stream>>>(deg, off, bsum, N_NODES_C);
    k_scan2<<<1, 128, 0, stream>>>(bsum, nb);
    k_scan3<<<nb, 1024, 0, stream>>>(off, cursor, bsum, N_NODES_C, N_EDGES_C);
    k_edge_b<<<(N_EDGES_C+255)/256, 256, 0, stream>>>(trip, sA, sB, sR, sConst,
                                                      cursor, key, bval, N_EDGES_C);
    k_aggregate<<<(N_NODES_C+7)/8, 256, 0, stream>>>(off, key, bval, BnB, Rm, biasC,
                                                     h, N_NODES_C);
}